// Round 3
// baseline (514.574 us; speedup 1.0000x reference)
//
#include <hip/hip_runtime.h>
#include <math.h>

#define BB 2
#define QQ 4
#define NH 32
#define NKV 8
#define GRP 4      // NH / NKV
#define HD 128
#define DM 4096
#define KVN 4096
#define SL 4100    // KVN + QQ
#define RK 410     // top-k remain
#define NCOLS 6144 // 4096 (Wq) + 1024 (Wk) + 1024 (Wv)
#define K1 ((float)(0.08838834764831845 * 1.4426950408889634))  // (1/sqrt(128))*log2(e)
#define NSC 16
#define SCH 260    // 16*260 = 4160 >= 4100

typedef float f4 __attribute__((ext_vector_type(4)));

__device__ __forceinline__ f4 nt4(const float* p) {
    return __builtin_nontemporal_load((const f4*)p);
}
__device__ __forceinline__ f4 ld4(const float* p) {
    return *(const f4*)p;
}

// ---------------- init: rope tables (fp64 trig) + zero accum buffers ----------------
// grid 1025 x 256 == SL*64 threads exactly
__global__ __launch_bounds__(256) void k_init(float* __restrict__ cos_t,
                                              float* __restrict__ sin_t,
                                              float* __restrict__ qkv,
                                              float* __restrict__ attn,
                                              float* __restrict__ out) {
    int idx = blockIdx.x * 256 + threadIdx.x;
    if (idx < 49152)        qkv[idx] = 0.f;
    else if (idx < 81920)   attn[idx - 49152] = 0.f;
    else if (idx < 114688)  out[idx - 81920] = 0.f;
    int s = idx >> 6, i = idx & 63;
    double inv = pow(10000.0, -(double)i / 64.0);
    double f = (double)s * inv;
    cos_t[idx] = (float)cos(f);
    sin_t[idx] = (float)sin(f);
}

// ---------------- QKV projection: atomic partial sums into qkv[8][6144] ----------------
// grid (12, 32), block 128: block covers 512 cols x 128 depth
__global__ __launch_bounds__(128) void k_proj(const float* __restrict__ hs,
                                              const float* __restrict__ Wq,
                                              const float* __restrict__ Wk,
                                              const float* __restrict__ Wv,
                                              float* __restrict__ qkv) {
    int c4 = (blockIdx.x * 128 + threadIdx.x) * 4;
    int d0 = blockIdx.y * 128;
    const float* Wp; int ld, cc;
    if (c4 < 4096)      { Wp = Wq; ld = 4096; cc = c4; }
    else if (c4 < 5120) { Wp = Wk; ld = 1024; cc = c4 - 4096; }
    else                { Wp = Wv; ld = 1024; cc = c4 - 5120; }
    float acc[8][4] = {};
    const float* hp = hs + d0;
    const float* wp = Wp + (size_t)d0 * ld + cc;
    #pragma unroll 4
    for (int d = 0; d < 128; ++d) {
        f4 w = nt4(wp + (size_t)d * ld);
        #pragma unroll
        for (int r = 0; r < 8; ++r) {
            float hv = hp[r * DM + d];
            acc[r][0] = fmaf(hv, w.x, acc[r][0]);
            acc[r][1] = fmaf(hv, w.y, acc[r][1]);
            acc[r][2] = fmaf(hv, w.z, acc[r][2]);
            acc[r][3] = fmaf(hv, w.w, acc[r][3]);
        }
    }
    #pragma unroll
    for (int r = 0; r < 8; ++r)
        #pragma unroll
        for (int e = 0; e < 4; ++e)
            atomicAdd(&qkv[(size_t)r * NCOLS + c4 + e], acc[r][e]);
}

// ---------------- rope q / new-k, copy new-v ----------------
__global__ __launch_bounds__(256) void k_rope(const float* __restrict__ qkv,
                                              const float* __restrict__ cos_t,
                                              const float* __restrict__ sin_t,
                                              float* __restrict__ q_r,
                                              float* __restrict__ kn_r,
                                              float* __restrict__ v_new) {
    int idx = blockIdx.x * 256 + threadIdx.x;   // exactly 24576 = 96*256
    int r = idx / 3072, t = idx % 3072;
    int b = r / QQ, qi = r % QQ;
    int pos = KVN + qi;
    int c_lo, c_hi;
    if (t < 2048)      { int hh = t >> 6, i = t & 63; c_lo = hh * 128 + i; c_hi = c_lo + 64; }
    else if (t < 2560) { int kh = (t - 2048) >> 6, i = (t - 2048) & 63; c_lo = 4096 + kh * 128 + i; c_hi = c_lo + 64; }
    else               { c_lo = 5120 + ((t - 2560) << 1); c_hi = c_lo + 1; }
    float x_lo = qkv[(size_t)r * NCOLS + c_lo];
    float x_hi = qkv[(size_t)r * NCOLS + c_hi];
    if (t < 2048) {
        int hh = t >> 6, i = t & 63;
        float cv = cos_t[pos * 64 + i], sv = sin_t[pos * 64 + i];
        float* dst = q_r + (((size_t)(b * NH + hh) * QQ + qi) * HD);
        dst[i]      = x_lo * cv - x_hi * sv;
        dst[i + 64] = x_hi * cv + x_lo * sv;
    } else if (t < 2560) {
        int kh = (t - 2048) >> 6, i = (t - 2048) & 63;
        float cv = cos_t[pos * 64 + i], sv = sin_t[pos * 64 + i];
        float* dst = kn_r + (((size_t)(b * NKV + kh) * QQ + qi) * HD);
        dst[i]      = x_lo * cv - x_hi * sv;
        dst[i + 64] = x_hi * cv + x_lo * sv;
    } else {
        int cv = c_lo - 5120;
        int kh = cv >> 7, dd = cv & 127;
        float* dst = v_new + (((size_t)(b * NKV + kh) * QQ + qi) * HD);
        dst[dd] = x_lo;
        dst[dd + 1] = x_hi;
    }
}

__device__ __forceinline__ float dot8(f4 a, f4 b, f4 qa, f4 qb) {
    return a.x*qa.x + a.y*qa.y + a.z*qa.z + a.w*qa.w
         + b.x*qb.x + b.y*qb.y + b.z*qb.z + b.w*qb.w;
}

// ---------------- draft scores: 4 s-rows per wave-iter, width-16 reduce ----------------
// grid (64, NSC), block 256
__global__ __launch_bounds__(256) void k_score(const float* __restrict__ q_r,
                                               const float* __restrict__ kn_r,
                                               const float* __restrict__ k_cache,
                                               const float* __restrict__ cos_t,
                                               const float* __restrict__ sin_t,
                                               float* __restrict__ draft) {
    int bh = blockIdx.x, b = bh >> 5, hh = bh & 31;
    int tid = threadIdx.x, wave = tid >> 6, lane = tid & 63;
    int sgrp = lane >> 4, dq = (lane & 15) * 4;
    f4 qlo[4], qhi[4];
    const float* qb = q_r + (size_t)bh * QQ * HD;
    #pragma unroll
    for (int qi = 0; qi < 4; ++qi) {
        qlo[qi] = ld4(qb + qi * HD + dq);
        qhi[qi] = ld4(qb + qi * HD + dq + 64);
    }
    int s0 = blockIdx.y * SCH;
    int s1 = s0 + SCH; if (s1 > SL) s1 = SL;
    const float* knb = kn_r + ((size_t)(b * NKV + (hh >> 2)) * QQ) * HD;
    float* db = draft + (size_t)bh * QQ * SL;
    for (int s = s0 + wave * 4 + sgrp; s < s1; s += 16) {
        f4 lo, hi;
        if (s < KVN) {
            const float* kp = k_cache + ((size_t)bh * KVN + s) * HD;
            f4 klo = nt4(kp + dq);
            f4 khi = nt4(kp + dq + 64);
            f4 c4 = ld4(cos_t + (size_t)s * 64 + dq);
            f4 s4 = ld4(sin_t + (size_t)s * 64 + dq);
            lo = klo * c4 - khi * s4;
            hi = khi * c4 + klo * s4;
        } else {
            const float* kp = knb + (size_t)(s - KVN) * HD;
            lo = ld4(kp + dq);
            hi = ld4(kp + dq + 64);
        }
        float p0 = dot8(lo, hi, qlo[0], qhi[0]);
        float p1 = dot8(lo, hi, qlo[1], qhi[1]);
        float p2 = dot8(lo, hi, qlo[2], qhi[2]);
        float p3 = dot8(lo, hi, qlo[3], qhi[3]);
        #pragma unroll
        for (int off = 8; off; off >>= 1) {
            p0 += __shfl_down(p0, off, 16);
            p1 += __shfl_down(p1, off, 16);
            p2 += __shfl_down(p2, off, 16);
            p3 += __shfl_down(p3, off, 16);
        }
        if ((lane & 15) == 0) {
            db[0 * SL + s] = p0;
            db[1 * SL + s] = p1;
            db[2 * SL + s] = p2;
            db[3 * SL + s] = p3;
        }
    }
}

// ---------------- top-k threshold + incremental exp-sum (no max pass) ----------------
__device__ __forceinline__ unsigned int okey(float f) {
    unsigned int u = __float_as_uint(f);
    return (u & 0x80000000u) ? ~u : (u | 0x80000000u);
}

// grid 256 (one row each), block 256. Scores |v| < ~60 so 2^(v*K1) is fp32-safe unnormalized.
__global__ __launch_bounds__(256) void k_topk(const float* __restrict__ draft,
                                              float* __restrict__ thr,
                                              float* __restrict__ c2) {
    int row = blockIdx.x;
    const f4* sc4 = (const f4*)(draft + (size_t)row * SL);  // 1025 vec4s
    __shared__ unsigned int hist[256];
    __shared__ float ehist[256];
    __shared__ unsigned int s_prefix;
    __shared__ int s_remain;
    __shared__ float s_esum;
    int tid = threadIdx.x;
    unsigned int prefix = 0;
    int remain = RK;
    if (tid == 0) s_esum = 0.f;
    for (int pass = 3; pass >= 0; --pass) {
        hist[tid] = 0;
        ehist[tid] = 0.f;
        __syncthreads();
        int shift = pass * 8;
        for (int i = tid; i < 1025; i += 256) {
            f4 v = sc4[i];
            float vv[4] = {v.x, v.y, v.z, v.w};
            #pragma unroll
            for (int e = 0; e < 4; ++e) {
                unsigned int k = okey(vv[e]);
                if (pass == 3 || (k >> (shift + 8)) == prefix) {
                    unsigned int bb = (k >> shift) & 0xFFu;
                    atomicAdd(&hist[bb], 1u);
                    atomicAdd(&ehist[bb], exp2f(vv[e] * K1));
                }
            }
        }
        __syncthreads();
        if (tid == 0) {
            int cum = 0, bsel = 0;
            float es = 0.f;
            for (int bb = 255; bb >= 0; --bb) {
                int c = (int)hist[bb];
                if (cum + c >= remain) { bsel = bb; break; }
                cum += c;
                es += ehist[bb];
            }
            if (pass == 0) es += ehist[bsel];  // boundary elems (v == thr) are included
            s_esum += es;
            s_prefix = (pass == 3) ? (unsigned int)bsel : ((prefix << 8) | (unsigned int)bsel);
            s_remain = remain - cum;
        }
        __syncthreads();
        prefix = s_prefix;
        remain = s_remain;
        __syncthreads();
    }
    if (tid == 0) {
        unsigned int u = (prefix & 0x80000000u) ? (prefix ^ 0x80000000u) : ~prefix;
        thr[row] = __uint_as_float(u);
        c2[row] = -log2f(s_esum);
    }
}

// ---------------- P @ V: skip v-rows where no query includes them ----------------
// grid (64, NSC), block 256
__global__ __launch_bounds__(256) void k_pv(const float* __restrict__ draft,
                                            const float* __restrict__ thr,
                                            const float* __restrict__ c2,
                                            const float* __restrict__ v_cache,
                                            const float* __restrict__ v_new,
                                            float* __restrict__ attn_acc) {
    int bh = blockIdx.x, b = bh >> 5, hh = bh & 31;
    int tid = threadIdx.x, wave = tid >> 6, lane = tid & 63;
    int sh = lane >> 5, dq = (lane & 31) * 4;
    float thr4[4], c24[4];
    #pragma unroll
    for (int qi = 0; qi < 4; ++qi) {
        thr4[qi] = thr[bh * QQ + qi];
        c24[qi] = c2[bh * QQ + qi];
    }
    int s0 = blockIdx.y * SCH;
    int s1 = s0 + SCH; if (s1 > SL) s1 = SL;
    const float* sc0 = draft + (size_t)bh * QQ * SL;
    const float* vnb = v_new + ((size_t)(b * NKV + (hh >> 2)) * QQ) * HD;
    float acc[4][4] = {};
    for (int s = s0 + wave * 2 + sh; s < s1; s += 8) {
        float sv0 = sc0[0 * SL + s];
        float sv1 = sc0[1 * SL + s];
        float sv2 = sc0[2 * SL + s];
        float sv3 = sc0[3 * SL + s];
        bool i0 = sv0 >= thr4[0], i1 = sv1 >= thr4[1];
        bool i2 = sv2 >= thr4[2], i3 = sv3 >= thr4[3];
        if (i0 | i1 | i2 | i3) {    // uniform per 32-lane half -> clean skip
            const float* vp = (s < KVN) ? v_cache + ((size_t)bh * KVN + s) * HD
                                        : vnb + (size_t)(s - KVN) * HD;
            f4 v4 = nt4(vp + dq);
            float w0 = i0 ? exp2f(fmaf(sv0, K1, c24[0])) : 0.f;
            float w1 = i1 ? exp2f(fmaf(sv1, K1, c24[1])) : 0.f;
            float w2 = i2 ? exp2f(fmaf(sv2, K1, c24[2])) : 0.f;
            float w3 = i3 ? exp2f(fmaf(sv3, K1, c24[3])) : 0.f;
            acc[0][0] = fmaf(w0, v4.x, acc[0][0]); acc[0][1] = fmaf(w0, v4.y, acc[0][1]);
            acc[0][2] = fmaf(w0, v4.z, acc[0][2]); acc[0][3] = fmaf(w0, v4.w, acc[0][3]);
            acc[1][0] = fmaf(w1, v4.x, acc[1][0]); acc[1][1] = fmaf(w1, v4.y, acc[1][1]);
            acc[1][2] = fmaf(w1, v4.z, acc[1][2]); acc[1][3] = fmaf(w1, v4.w, acc[1][3]);
            acc[2][0] = fmaf(w2, v4.x, acc[2][0]); acc[2][1] = fmaf(w2, v4.y, acc[2][1]);
            acc[2][2] = fmaf(w2, v4.z, acc[2][2]); acc[2][3] = fmaf(w2, v4.w, acc[2][3]);
            acc[3][0] = fmaf(w3, v4.x, acc[3][0]); acc[3][1] = fmaf(w3, v4.y, acc[3][1]);
            acc[3][2] = fmaf(w3, v4.z, acc[3][2]); acc[3][3] = fmaf(w3, v4.w, acc[3][3]);
        }
    }
    // combine the two half-wave s-streams
    #pragma unroll
    for (int qi = 0; qi < 4; ++qi)
        #pragma unroll
        for (int e = 0; e < 4; ++e)
            acc[qi][e] += __shfl_down(acc[qi][e], 32);
    __shared__ float accs[4][4][128];   // 8 KB: [wave][qi][d]
    if (lane < 32) {
        #pragma unroll
        for (int qi = 0; qi < 4; ++qi)
            *(float4*)&accs[wave][qi][dq] = make_float4(acc[qi][0], acc[qi][1], acc[qi][2], acc[qi][3]);
    }
    __syncthreads();
    for (int e = tid; e < 512; e += 256) {
        int qi = e >> 7, dd = e & 127;
        float sum = accs[0][qi][dd] + accs[1][qi][dd] + accs[2][qi][dd] + accs[3][qi][dd];
        atomicAdd(&attn_acc[(size_t)(b * QQ + qi) * DM + hh * HD + dd], sum);
    }
}

// ---------------- output projection: out += attn_flat @ Wo ----------------
// grid (8, 32), block 128
__global__ __launch_bounds__(128) void k_oproj(const float* __restrict__ attn_flat,
                                               const float* __restrict__ Wo,
                                               float* __restrict__ out) {
    int c4 = (blockIdx.x * 128 + threadIdx.x) * 4;
    int d0 = blockIdx.y * 128;
    float acc[8][4] = {};
    const float* ap = attn_flat + d0;
    const float* wp = Wo + (size_t)d0 * DM + c4;
    #pragma unroll 4
    for (int d = 0; d < 128; ++d) {
        f4 w = nt4(wp + (size_t)d * DM);
        #pragma unroll
        for (int r = 0; r < 8; ++r) {
            float hv = ap[r * DM + d];
            acc[r][0] = fmaf(hv, w.x, acc[r][0]);
            acc[r][1] = fmaf(hv, w.y, acc[r][1]);
            acc[r][2] = fmaf(hv, w.z, acc[r][2]);
            acc[r][3] = fmaf(hv, w.w, acc[r][3]);
        }
    }
    #pragma unroll
    for (int r = 0; r < 8; ++r)
        #pragma unroll
        for (int e = 0; e < 4; ++e)
            atomicAdd(&out[(size_t)r * DM + c4 + e], acc[r][e]);
}

extern "C" void kernel_launch(void* const* d_in, const int* in_sizes, int n_in,
                              void* d_out, int out_size, void* d_ws, size_t ws_size,
                              hipStream_t stream) {
    const float* hs      = (const float*)d_in[0];
    const float* k_cache = (const float*)d_in[1];
    const float* v_cache = (const float*)d_in[2];
    const float* Wq      = (const float*)d_in[3];
    const float* Wk      = (const float*)d_in[4];
    const float* Wv      = (const float*)d_in[5];
    const float* Wo      = (const float*)d_in[6];
    float* out = (float*)d_out;
    float* ws  = (float*)d_ws;

    float* qkv   = ws;                 // 49152
    float* q_r   = ws + 49152;         // 32768
    float* kn_r  = ws + 81920;         // 8192
    float* v_new = ws + 90112;         // 8192
    float* cos_t = ws + 98304;         // 262400
    float* sin_t = ws + 360704;        // 262400
    float* draft = ws + 623104;        // 1049600
    float* thr   = ws + 1672704;       // 256
    float* c2    = ws + 1672960;       // 256
    float* attn  = ws + 1673216;       // 32768 -> end 1705984 floats (~6.8 MB)

    k_init<<<dim3(1025), dim3(256), 0, stream>>>(cos_t, sin_t, qkv, attn, out);
    k_proj<<<dim3(12, 32), dim3(128), 0, stream>>>(hs, Wq, Wk, Wv, qkv);
    k_rope<<<dim3(96), dim3(256), 0, stream>>>(qkv, cos_t, sin_t, q_r, kn_r, v_new);
    k_score<<<dim3(BB * NH, NSC), dim3(256), 0, stream>>>(q_r, kn_r, k_cache, cos_t, sin_t, draft);
    k_topk<<<dim3(BB * NH * QQ), dim3(256), 0, stream>>>(draft, thr, c2);
    k_pv<<<dim3(BB * NH, NSC), dim3(256), 0, stream>>>(draft, thr, c2, v_cache, v_new, attn);
    k_oproj<<<dim3(8, 32), dim3(128), 0, stream>>>(attn, Wo, out);
}

// Round 4
// 443.614 us; speedup vs baseline: 1.1600x; 1.1600x over previous
//
#include <hip/hip_runtime.h>
#include <math.h>

#define BB 2
#define QQ 4
#define NH 32
#define NKV 8
#define GRP 4      // NH / NKV
#define HD 128
#define DM 4096
#define KVN 4096
#define SL 4100    // KVN + QQ
#define RK 410     // top-k remain
#define NCOLS 6144 // 4096 (Wq) + 1024 (Wk) + 1024 (Wv)
#define K1 ((float)(0.08838834764831845 * 1.4426950408889634))  // (1/sqrt(128))*log2(e)
#define NSC 16
#define SCH 260    // 16*260 = 4160 >= 4100

typedef float f4 __attribute__((ext_vector_type(4)));

__device__ __forceinline__ f4 nt4(const float* p) {
    return __builtin_nontemporal_load((const f4*)p);
}
__device__ __forceinline__ f4 ld4(const float* p) {
    return *(const f4*)p;
}

// ---------------- init: rope tables (fp64 trig) + zero accum buffers ----------------
// grid 1025 x 256 == SL*64 threads exactly
__global__ __launch_bounds__(256) void k_init(float* __restrict__ cos_t,
                                              float* __restrict__ sin_t,
                                              float* __restrict__ qkv,
                                              float* __restrict__ attn,
                                              float* __restrict__ out) {
    int idx = blockIdx.x * 256 + threadIdx.x;
    if (idx < 49152)        qkv[idx] = 0.f;
    else if (idx < 81920)   attn[idx - 49152] = 0.f;
    else if (idx < 114688)  out[idx - 81920] = 0.f;
    int s = idx >> 6, i = idx & 63;
    double inv = pow(10000.0, -(double)i / 64.0);
    double f = (double)s * inv;
    cos_t[idx] = (float)cos(f);
    sin_t[idx] = (float)sin(f);
}

// ---------------- QKV projection: atomic partial sums into qkv[8][6144] ----------------
// grid (12, 32), block 128: block covers 512 cols x 128 depth
__global__ __launch_bounds__(128) void k_proj(const float* __restrict__ hs,
                                              const float* __restrict__ Wq,
                                              const float* __restrict__ Wk,
                                              const float* __restrict__ Wv,
                                              float* __restrict__ qkv) {
    int c4 = (blockIdx.x * 128 + threadIdx.x) * 4;
    int d0 = blockIdx.y * 128;
    const float* Wp; int ld, cc;
    if (c4 < 4096)      { Wp = Wq; ld = 4096; cc = c4; }
    else if (c4 < 5120) { Wp = Wk; ld = 1024; cc = c4 - 4096; }
    else                { Wp = Wv; ld = 1024; cc = c4 - 5120; }
    float acc[8][4] = {};
    const float* hp = hs + d0;
    const float* wp = Wp + (size_t)d0 * ld + cc;
    #pragma unroll 4
    for (int d = 0; d < 128; ++d) {
        f4 w = nt4(wp + (size_t)d * ld);
        #pragma unroll
        for (int r = 0; r < 8; ++r) {
            float hv = hp[r * DM + d];
            acc[r][0] = fmaf(hv, w.x, acc[r][0]);
            acc[r][1] = fmaf(hv, w.y, acc[r][1]);
            acc[r][2] = fmaf(hv, w.z, acc[r][2]);
            acc[r][3] = fmaf(hv, w.w, acc[r][3]);
        }
    }
    #pragma unroll
    for (int r = 0; r < 8; ++r)
        #pragma unroll
        for (int e = 0; e < 4; ++e)
            atomicAdd(&qkv[(size_t)r * NCOLS + c4 + e], acc[r][e]);
}

// ---------------- rope q / new-k, copy new-v ----------------
__global__ __launch_bounds__(256) void k_rope(const float* __restrict__ qkv,
                                              const float* __restrict__ cos_t,
                                              const float* __restrict__ sin_t,
                                              float* __restrict__ q_r,
                                              float* __restrict__ kn_r,
                                              float* __restrict__ v_new) {
    int idx = blockIdx.x * 256 + threadIdx.x;   // exactly 24576 = 96*256
    int r = idx / 3072, t = idx % 3072;
    int b = r / QQ, qi = r % QQ;
    int pos = KVN + qi;
    int c_lo, c_hi;
    if (t < 2048)      { int hh = t >> 6, i = t & 63; c_lo = hh * 128 + i; c_hi = c_lo + 64; }
    else if (t < 2560) { int kh = (t - 2048) >> 6, i = (t - 2048) & 63; c_lo = 4096 + kh * 128 + i; c_hi = c_lo + 64; }
    else               { c_lo = 5120 + ((t - 2560) << 1); c_hi = c_lo + 1; }
    float x_lo = qkv[(size_t)r * NCOLS + c_lo];
    float x_hi = qkv[(size_t)r * NCOLS + c_hi];
    if (t < 2048) {
        int hh = t >> 6, i = t & 63;
        float cv = cos_t[pos * 64 + i], sv = sin_t[pos * 64 + i];
        float* dst = q_r + (((size_t)(b * NH + hh) * QQ + qi) * HD);
        dst[i]      = x_lo * cv - x_hi * sv;
        dst[i + 64] = x_hi * cv + x_lo * sv;
    } else if (t < 2560) {
        int kh = (t - 2048) >> 6, i = (t - 2048) & 63;
        float cv = cos_t[pos * 64 + i], sv = sin_t[pos * 64 + i];
        float* dst = kn_r + (((size_t)(b * NKV + kh) * QQ + qi) * HD);
        dst[i]      = x_lo * cv - x_hi * sv;
        dst[i + 64] = x_hi * cv + x_lo * sv;
    } else {
        int cv = c_lo - 5120;
        int kh = cv >> 7, dd = cv & 127;
        float* dst = v_new + (((size_t)(b * NKV + kh) * QQ + qi) * HD);
        dst[dd] = x_lo;
        dst[dd + 1] = x_hi;
    }
}

__device__ __forceinline__ float dot8(f4 a, f4 b, f4 qa, f4 qb) {
    return a.x*qa.x + a.y*qa.y + a.z*qa.z + a.w*qa.w
         + b.x*qb.x + b.y*qb.y + b.z*qb.z + b.w*qb.w;
}

// ---------------- draft scores: 4 s-rows per wave-iter, width-16 reduce ----------------
// grid (64, NSC), block 256
__global__ __launch_bounds__(256) void k_score(const float* __restrict__ q_r,
                                               const float* __restrict__ kn_r,
                                               const float* __restrict__ k_cache,
                                               const float* __restrict__ cos_t,
                                               const float* __restrict__ sin_t,
                                               float* __restrict__ draft) {
    int bh = blockIdx.x, b = bh >> 5, hh = bh & 31;
    int tid = threadIdx.x, wave = tid >> 6, lane = tid & 63;
    int sgrp = lane >> 4, dq = (lane & 15) * 4;
    f4 qlo[4], qhi[4];
    const float* qb = q_r + (size_t)bh * QQ * HD;
    #pragma unroll
    for (int qi = 0; qi < 4; ++qi) {
        qlo[qi] = ld4(qb + qi * HD + dq);
        qhi[qi] = ld4(qb + qi * HD + dq + 64);
    }
    int s0 = blockIdx.y * SCH;
    int s1 = s0 + SCH; if (s1 > SL) s1 = SL;
    const float* knb = kn_r + ((size_t)(b * NKV + (hh >> 2)) * QQ) * HD;
    float* db = draft + (size_t)bh * QQ * SL;
    for (int s = s0 + wave * 4 + sgrp; s < s1; s += 16) {
        f4 lo, hi;
        if (s < KVN) {
            const float* kp = k_cache + ((size_t)bh * KVN + s) * HD;
            f4 klo = nt4(kp + dq);
            f4 khi = nt4(kp + dq + 64);
            f4 c4 = ld4(cos_t + (size_t)s * 64 + dq);
            f4 s4 = ld4(sin_t + (size_t)s * 64 + dq);
            lo = klo * c4 - khi * s4;
            hi = khi * c4 + klo * s4;
        } else {
            const float* kp = knb + (size_t)(s - KVN) * HD;
            lo = ld4(kp + dq);
            hi = ld4(kp + dq + 64);
        }
        float p0 = dot8(lo, hi, qlo[0], qhi[0]);
        float p1 = dot8(lo, hi, qlo[1], qhi[1]);
        float p2 = dot8(lo, hi, qlo[2], qhi[2]);
        float p3 = dot8(lo, hi, qlo[3], qhi[3]);
        #pragma unroll
        for (int off = 8; off; off >>= 1) {
            p0 += __shfl_down(p0, off, 16);
            p1 += __shfl_down(p1, off, 16);
            p2 += __shfl_down(p2, off, 16);
            p3 += __shfl_down(p3, off, 16);
        }
        if ((lane & 15) == 0) {
            db[0 * SL + s] = p0;
            db[1 * SL + s] = p1;
            db[2 * SL + s] = p2;
            db[3 * SL + s] = p3;
        }
    }
}

// ---------------- top-k threshold + exp-sum ----------------
__device__ __forceinline__ unsigned int okey(float f) {
    unsigned int u = __float_as_uint(f);
    return (u & 0x80000000u) ? ~u : (u | 0x80000000u);
}

// grid 256 (one row each), block 512 (8 waves).
// Per-wave privatized histograms (u32 only); parallel suffix-scan bin select;
// one final exp2 sweep for the softmax denominator (max-free, fp32-safe).
__global__ __launch_bounds__(512) void k_topk(const float* __restrict__ draft,
                                              float* __restrict__ thr,
                                              float* __restrict__ c2) {
    int row = blockIdx.x;
    const f4* sc4 = (const f4*)(draft + (size_t)row * SL);  // 1025 vec4s
    __shared__ unsigned int hist[8][256];
    __shared__ unsigned int sfx[256];
    __shared__ float redf[8];
    __shared__ unsigned int s_prefix;
    __shared__ int s_remain;
    int tid = threadIdx.x, wave = tid >> 6, lane = tid & 63;
    unsigned int* myhist = hist[wave];
    unsigned int prefix = 0;
    int remain = RK;
    for (int pass = 3; pass >= 0; --pass) {
        // clear private hists
        unsigned int* hflat = &hist[0][0];
        #pragma unroll
        for (int i = 0; i < 4; ++i) hflat[tid + i * 512] = 0;
        __syncthreads();
        int shift = pass * 8;
        for (int i = tid; i < 1025; i += 512) {
            f4 v = sc4[i];
            float vv[4] = {v.x, v.y, v.z, v.w};
            #pragma unroll
            for (int e = 0; e < 4; ++e) {
                unsigned int k = okey(vv[e]);
                if (pass == 3 || (k >> (shift + 8)) == prefix)
                    atomicAdd(&myhist[(k >> shift) & 0xFFu], 1u);
            }
        }
        __syncthreads();
        // combine 8 private hists -> sfx[b]
        if (tid < 256) {
            unsigned int t = 0;
            #pragma unroll
            for (int w = 0; w < 8; ++w) t += hist[w][tid];
            sfx[tid] = t;
        }
        __syncthreads();
        // suffix sum (Hillis-Steele, from the top)
        #pragma unroll
        for (int st = 1; st < 256; st <<= 1) {
            unsigned int v = 0;
            if (tid < 256 && tid + st < 256) v = sfx[tid + st];
            __syncthreads();
            if (tid < 256) sfx[tid] += v;
            __syncthreads();
        }
        // select bin: largest b with sfx[b] >= remain
        if (tid < 256) {
            unsigned int me = sfx[tid];
            unsigned int nxt = (tid < 255) ? sfx[tid + 1] : 0u;
            if (me >= (unsigned int)remain && nxt < (unsigned int)remain) {
                s_prefix = (pass == 3) ? (unsigned int)tid
                                       : ((prefix << 8) | (unsigned int)tid);
                s_remain = remain - (int)nxt;
            }
        }
        __syncthreads();
        prefix = s_prefix;
        remain = s_remain;
        __syncthreads();
    }
    unsigned int u = (prefix & 0x80000000u) ? (prefix ^ 0x80000000u) : ~prefix;
    float thrv = __uint_as_float(u);
    // exp-sum over included (v >= thrv); scores bounded so unnormalized 2^x is safe
    float ls = 0.f;
    for (int i = tid; i < 1025; i += 512) {
        f4 v = sc4[i];
        if (v.x >= thrv) ls += exp2f(v.x * K1);
        if (v.y >= thrv) ls += exp2f(v.y * K1);
        if (v.z >= thrv) ls += exp2f(v.z * K1);
        if (v.w >= thrv) ls += exp2f(v.w * K1);
    }
    #pragma unroll
    for (int off = 32; off; off >>= 1) ls += __shfl_down(ls, off);
    if (lane == 0) redf[wave] = ls;
    __syncthreads();
    if (tid == 0) {
        float t = redf[0] + redf[1] + redf[2] + redf[3]
                + redf[4] + redf[5] + redf[6] + redf[7];
        thr[row] = thrv;
        c2[row] = -log2f(t);
    }
}

// ---------------- P @ V: skip v-rows where no query includes them ----------------
// grid (64, NSC), block 256
__global__ __launch_bounds__(256) void k_pv(const float* __restrict__ draft,
                                            const float* __restrict__ thr,
                                            const float* __restrict__ c2,
                                            const float* __restrict__ v_cache,
                                            const float* __restrict__ v_new,
                                            float* __restrict__ attn_acc) {
    int bh = blockIdx.x, b = bh >> 5, hh = bh & 31;
    int tid = threadIdx.x, wave = tid >> 6, lane = tid & 63;
    int sh = lane >> 5, dq = (lane & 31) * 4;
    float thr4[4], c24[4];
    #pragma unroll
    for (int qi = 0; qi < 4; ++qi) {
        thr4[qi] = thr[bh * QQ + qi];
        c24[qi] = c2[bh * QQ + qi];
    }
    int s0 = blockIdx.y * SCH;
    int s1 = s0 + SCH; if (s1 > SL) s1 = SL;
    const float* sc0 = draft + (size_t)bh * QQ * SL;
    const float* vnb = v_new + ((size_t)(b * NKV + (hh >> 2)) * QQ) * HD;
    float acc[4][4] = {};
    for (int s = s0 + wave * 2 + sh; s < s1; s += 8) {
        float sv0 = sc0[0 * SL + s];
        float sv1 = sc0[1 * SL + s];
        float sv2 = sc0[2 * SL + s];
        float sv3 = sc0[3 * SL + s];
        bool i0 = sv0 >= thr4[0], i1 = sv1 >= thr4[1];
        bool i2 = sv2 >= thr4[2], i3 = sv3 >= thr4[3];
        if (i0 | i1 | i2 | i3) {    // uniform per 32-lane half -> clean skip
            const float* vp = (s < KVN) ? v_cache + ((size_t)bh * KVN + s) * HD
                                        : vnb + (size_t)(s - KVN) * HD;
            f4 v4 = nt4(vp + dq);
            float w0 = i0 ? exp2f(fmaf(sv0, K1, c24[0])) : 0.f;
            float w1 = i1 ? exp2f(fmaf(sv1, K1, c24[1])) : 0.f;
            float w2 = i2 ? exp2f(fmaf(sv2, K1, c24[2])) : 0.f;
            float w3 = i3 ? exp2f(fmaf(sv3, K1, c24[3])) : 0.f;
            acc[0][0] = fmaf(w0, v4.x, acc[0][0]); acc[0][1] = fmaf(w0, v4.y, acc[0][1]);
            acc[0][2] = fmaf(w0, v4.z, acc[0][2]); acc[0][3] = fmaf(w0, v4.w, acc[0][3]);
            acc[1][0] = fmaf(w1, v4.x, acc[1][0]); acc[1][1] = fmaf(w1, v4.y, acc[1][1]);
            acc[1][2] = fmaf(w1, v4.z, acc[1][2]); acc[1][3] = fmaf(w1, v4.w, acc[1][3]);
            acc[2][0] = fmaf(w2, v4.x, acc[2][0]); acc[2][1] = fmaf(w2, v4.y, acc[2][1]);
            acc[2][2] = fmaf(w2, v4.z, acc[2][2]); acc[2][3] = fmaf(w2, v4.w, acc[2][3]);
            acc[3][0] = fmaf(w3, v4.x, acc[3][0]); acc[3][1] = fmaf(w3, v4.y, acc[3][1]);
            acc[3][2] = fmaf(w3, v4.z, acc[3][2]); acc[3][3] = fmaf(w3, v4.w, acc[3][3]);
        }
    }
    // combine the two half-wave s-streams
    #pragma unroll
    for (int qi = 0; qi < 4; ++qi)
        #pragma unroll
        for (int e = 0; e < 4; ++e)
            acc[qi][e] += __shfl_down(acc[qi][e], 32);
    __shared__ float accs[4][4][128];   // 8 KB: [wave][qi][d]
    if (lane < 32) {
        #pragma unroll
        for (int qi = 0; qi < 4; ++qi)
            *(float4*)&accs[wave][qi][dq] = make_float4(acc[qi][0], acc[qi][1], acc[qi][2], acc[qi][3]);
    }
    __syncthreads();
    for (int e = tid; e < 512; e += 256) {
        int qi = e >> 7, dd = e & 127;
        float sum = accs[0][qi][dd] + accs[1][qi][dd] + accs[2][qi][dd] + accs[3][qi][dd];
        atomicAdd(&attn_acc[(size_t)(b * QQ + qi) * DM + hh * HD + dd], sum);
    }
}

// ---------------- output projection: out += attn_flat @ Wo ----------------
// grid (8, 32), block 128
__global__ __launch_bounds__(128) void k_oproj(const float* __restrict__ attn_flat,
                                               const float* __restrict__ Wo,
                                               float* __restrict__ out) {
    int c4 = (blockIdx.x * 128 + threadIdx.x) * 4;
    int d0 = blockIdx.y * 128;
    float acc[8][4] = {};
    const float* ap = attn_flat + d0;
    const float* wp = Wo + (size_t)d0 * DM + c4;
    #pragma unroll 4
    for (int d = 0; d < 128; ++d) {
        f4 w = nt4(wp + (size_t)d * DM);
        #pragma unroll
        for (int r = 0; r < 8; ++r) {
            float hv = ap[r * DM + d];
            acc[r][0] = fmaf(hv, w.x, acc[r][0]);
            acc[r][1] = fmaf(hv, w.y, acc[r][1]);
            acc[r][2] = fmaf(hv, w.z, acc[r][2]);
            acc[r][3] = fmaf(hv, w.w, acc[r][3]);
        }
    }
    #pragma unroll
    for (int r = 0; r < 8; ++r)
        #pragma unroll
        for (int e = 0; e < 4; ++e)
            atomicAdd(&out[(size_t)r * DM + c4 + e], acc[r][e]);
}

extern "C" void kernel_launch(void* const* d_in, const int* in_sizes, int n_in,
                              void* d_out, int out_size, void* d_ws, size_t ws_size,
                              hipStream_t stream) {
    const float* hs      = (const float*)d_in[0];
    const float* k_cache = (const float*)d_in[1];
    const float* v_cache = (const float*)d_in[2];
    const float* Wq      = (const float*)d_in[3];
    const float* Wk      = (const float*)d_in[4];
    const float* Wv      = (const float*)d_in[5];
    const float* Wo      = (const float*)d_in[6];
    float* out = (float*)d_out;
    float* ws  = (float*)d_ws;

    float* qkv   = ws;                 // 49152
    float* q_r   = ws + 49152;         // 32768
    float* kn_r  = ws + 81920;         // 8192
    float* v_new = ws + 90112;         // 8192
    float* cos_t = ws + 98304;         // 262400
    float* sin_t = ws + 360704;        // 262400
    float* draft = ws + 623104;        // 1049600
    float* thr   = ws + 1672704;       // 256
    float* c2    = ws + 1672960;       // 256
    float* attn  = ws + 1673216;       // 32768 -> end 1705984 floats (~6.8 MB)

    k_init<<<dim3(1025), dim3(256), 0, stream>>>(cos_t, sin_t, qkv, attn, out);
    k_proj<<<dim3(12, 32), dim3(128), 0, stream>>>(hs, Wq, Wk, Wv, qkv);
    k_rope<<<dim3(96), dim3(256), 0, stream>>>(qkv, cos_t, sin_t, q_r, kn_r, v_new);
    k_score<<<dim3(BB * NH, NSC), dim3(256), 0, stream>>>(q_r, kn_r, k_cache, cos_t, sin_t, draft);
    k_topk<<<dim3(BB * NH * QQ), dim3(512), 0, stream>>>(draft, thr, c2);
    k_pv<<<dim3(BB * NH, NSC), dim3(256), 0, stream>>>(draft, thr, c2, v_cache, v_new, attn);
    k_oproj<<<dim3(8, 32), dim3(128), 0, stream>>>(attn, Wo, out);
}